// Round 2
// baseline (715.941 us; speedup 1.0000x reference)
//
#include <hip/hip_runtime.h>
#include <math.h>

#define DM 3136
#define DH 512

// ---------------- conv3x3 (SAME, NHWC semantics) + channel-RMSNorm ----------------
__global__ __launch_bounds__(256) void conv_rms(
    const float* __restrict__ x,
    const float* __restrict__ wk, const float* __restrict__ bk,
    const float* __restrict__ wv, const float* __restrict__ bv,
    const float* __restrict__ sk, const float* __restrict__ sv,
    float* __restrict__ nk, float* __restrict__ nv) {
  __shared__ float swk[144], swv[144], sb[16];
  int tid = threadIdx.x;
  if (tid < 144) { swk[tid] = wk[tid]; swv[tid] = wv[tid]; }
  if (tid < 4) {
    sb[tid] = bk[tid]; sb[4 + tid] = bv[tid];
    sb[8 + tid] = sk[tid]; sb[12 + tid] = sv[tid];
  }
  __syncthreads();
  int idx = blockIdx.x * 256 + tid;          // t*784 + hw, total 512*784
  int t = idx / 784, hw = idx - t * 784;
  int h = hw / 28, w = hw - h * 28;
  float ak[4], av[4];
  #pragma unroll
  for (int c = 0; c < 4; ++c) { ak[c] = sb[c]; av[c] = sb[4 + c]; }
  const float* xt = x + (size_t)t * DM;      // x[t, ci, ih, iw], ci stride 784
  for (int kh = 0; kh < 3; ++kh) {
    int ih = h + kh - 1;
    if (ih < 0 || ih >= 28) continue;
    for (int kw = 0; kw < 3; ++kw) {
      int iw = w + kw - 1;
      if (iw < 0 || iw >= 28) continue;
      int base = (kh * 3 + kw) * 16;
      #pragma unroll
      for (int ci = 0; ci < 4; ++ci) {
        float xv = xt[ci * 784 + ih * 28 + iw];
        #pragma unroll
        for (int co = 0; co < 4; ++co) {
          ak[co] += xv * swk[base + ci * 4 + co];
          av[co] += xv * swv[base + ci * 4 + co];
        }
      }
    }
  }
  float mk = (ak[0]*ak[0] + ak[1]*ak[1] + ak[2]*ak[2] + ak[3]*ak[3]) * 0.25f + 1e-6f;
  float mv = (av[0]*av[0] + av[1]*av[1] + av[2]*av[2] + av[3]*av[3]) * 0.25f + 1e-6f;
  float ik = 1.f / sqrtf(mk), iv = 1.f / sqrtf(mv);
  float4 ok = { ak[0]*ik*sb[8],  ak[1]*ik*sb[9],  ak[2]*ik*sb[10], ak[3]*ik*sb[11] };
  float4 ov = { av[0]*iv*sb[12], av[1]*iv*sb[13], av[2]*iv*sb[14], av[3]*iv*sb[15] };
  *(float4*)&nk[(size_t)idx * 4] = ok;   // nk[t][(h*28+w)*4 + c]
  *(float4*)&nv[(size_t)idx * 4] = ov;
}

// ---------------- GEMM pieces: A[64,K] @ B -> Cpart slices (split-K, 64 per slice) ----------------
// Tile 64m x 64n, full 64-k staged in LDS, 256 threads, 4x4 microtile.
__global__ __launch_bounds__(256) void mm64_nn(
    const float* __restrict__ A, int lda,
    const float* __restrict__ B, int ldb,
    float* __restrict__ Cp, int ldc) {
  __shared__ float As[64][64];   // As[k][m]
  __shared__ float Bs[64][64];   // Bs[k][n]
  int tid = threadIdx.x;
  int n0 = blockIdx.x * 64;
  int k0 = blockIdx.y * 64;
  {
    int m  = tid >> 2;
    int kb = (tid & 3) * 16;
    const float* Ap = A + (size_t)m * lda + k0 + kb;
    #pragma unroll
    for (int q = 0; q < 4; ++q) {
      float4 v = *(const float4*)(Ap + q * 4);
      As[kb + q*4 + 0][m] = v.x;
      As[kb + q*4 + 1][m] = v.y;
      As[kb + q*4 + 2][m] = v.z;
      As[kb + q*4 + 3][m] = v.w;
    }
    int kr = tid >> 4;
    int nn = (tid & 15) * 4;
    #pragma unroll
    for (int q = 0; q < 4; ++q) {
      float4 v = *(const float4*)(B + (size_t)(k0 + kr + q*16) * ldb + n0 + nn);
      *(float4*)&Bs[kr + q*16][nn] = v;
    }
  }
  __syncthreads();
  int tx = tid & 15, ty = tid >> 4;
  float acc[4][4] = {{0.f}};
  #pragma unroll 16
  for (int kk = 0; kk < 64; ++kk) {
    float4 a = *(const float4*)&As[kk][ty * 4];
    float4 b = *(const float4*)&Bs[kk][tx * 4];
    acc[0][0] += a.x*b.x; acc[0][1] += a.x*b.y; acc[0][2] += a.x*b.z; acc[0][3] += a.x*b.w;
    acc[1][0] += a.y*b.x; acc[1][1] += a.y*b.y; acc[1][2] += a.y*b.z; acc[1][3] += a.y*b.w;
    acc[2][0] += a.z*b.x; acc[2][1] += a.z*b.y; acc[2][2] += a.z*b.z; acc[2][3] += a.z*b.w;
    acc[3][0] += a.w*b.x; acc[3][1] += a.w*b.y; acc[3][2] += a.w*b.z; acc[3][3] += a.w*b.w;
  }
  float* Cb = Cp + (size_t)blockIdx.y * 64 * ldc + n0 + tx * 4;
  #pragma unroll
  for (int r = 0; r < 4; ++r) {
    float4 v = { acc[r][0], acc[r][1], acc[r][2], acc[r][3] };
    *(float4*)&Cb[(size_t)(ty * 4 + r) * ldc] = v;
  }
}

// A[64,K] @ B^T where B is [N,K] row-major (for Dw @ W2^T)
__global__ __launch_bounds__(256) void mm64_nt(
    const float* __restrict__ A, int lda,
    const float* __restrict__ B, int ldb,
    float* __restrict__ Cp, int ldc) {
  __shared__ float As[64][64];
  __shared__ float Bs[64][64];
  int tid = threadIdx.x;
  int n0 = blockIdx.x * 64;
  int k0 = blockIdx.y * 64;
  {
    int m  = tid >> 2;
    int kb = (tid & 3) * 16;
    const float* Ap = A + (size_t)m * lda + k0 + kb;
    const float* Bp = B + (size_t)(n0 + m) * ldb + k0 + kb;
    #pragma unroll
    for (int q = 0; q < 4; ++q) {
      float4 va = *(const float4*)(Ap + q * 4);
      As[kb + q*4 + 0][m] = va.x;
      As[kb + q*4 + 1][m] = va.y;
      As[kb + q*4 + 2][m] = va.z;
      As[kb + q*4 + 3][m] = va.w;
      float4 vb = *(const float4*)(Bp + q * 4);
      Bs[kb + q*4 + 0][m] = vb.x;
      Bs[kb + q*4 + 1][m] = vb.y;
      Bs[kb + q*4 + 2][m] = vb.z;
      Bs[kb + q*4 + 3][m] = vb.w;
    }
  }
  __syncthreads();
  int tx = tid & 15, ty = tid >> 4;
  float acc[4][4] = {{0.f}};
  #pragma unroll 16
  for (int kk = 0; kk < 64; ++kk) {
    float4 a = *(const float4*)&As[kk][ty * 4];
    float4 b = *(const float4*)&Bs[kk][tx * 4];
    acc[0][0] += a.x*b.x; acc[0][1] += a.x*b.y; acc[0][2] += a.x*b.z; acc[0][3] += a.x*b.w;
    acc[1][0] += a.y*b.x; acc[1][1] += a.y*b.y; acc[1][2] += a.y*b.z; acc[1][3] += a.y*b.w;
    acc[2][0] += a.z*b.x; acc[2][1] += a.z*b.y; acc[2][2] += a.z*b.z; acc[2][3] += a.z*b.w;
    acc[3][0] += a.w*b.x; acc[3][1] += a.w*b.y; acc[3][2] += a.w*b.z; acc[3][3] += a.w*b.w;
  }
  float* Cb = Cp + (size_t)blockIdx.y * 64 * ldc + n0 + tx * 4;
  #pragma unroll
  for (int r = 0; r < 4; ++r) {
    float4 v = { acc[r][0], acc[r][1], acc[r][2], acc[r][3] };
    *(float4*)&Cb[(size_t)(ty * 4 + r) * ldc] = v;
  }
}

// Rank-64 update: Cnew[P,Q] = Cold - A^T B,  A[64,P], B[64,Q]  (weights pre-folded into B)
__global__ __launch_bounds__(256) void upd64(
    const float* __restrict__ A, int P,
    const float* __restrict__ B, int Q,
    const float* __restrict__ Cold, float* __restrict__ Cnew) {
  __shared__ float As[64][64];   // As[i][p]
  __shared__ float Bs[64][64];   // Bs[i][q]
  int tid = threadIdx.x;
  int q0 = blockIdx.x * 64;
  int p0 = blockIdx.y * 64;
  {
    int i = tid >> 4;
    int c = (tid & 15) * 4;
    #pragma unroll
    for (int q = 0; q < 4; ++q) {
      *(float4*)&As[i + q*16][c] = *(const float4*)(A + (size_t)(i + q*16) * P + p0 + c);
      *(float4*)&Bs[i + q*16][c] = *(const float4*)(B + (size_t)(i + q*16) * Q + q0 + c);
    }
  }
  __syncthreads();
  int tx = tid & 15, ty = tid >> 4;
  float acc[4][4] = {{0.f}};
  #pragma unroll 16
  for (int i = 0; i < 64; ++i) {
    float4 a = *(const float4*)&As[i][ty * 4];
    float4 b = *(const float4*)&Bs[i][tx * 4];
    acc[0][0] += a.x*b.x; acc[0][1] += a.x*b.y; acc[0][2] += a.x*b.z; acc[0][3] += a.x*b.w;
    acc[1][0] += a.y*b.x; acc[1][1] += a.y*b.y; acc[1][2] += a.y*b.z; acc[1][3] += a.y*b.w;
    acc[2][0] += a.z*b.x; acc[2][1] += a.z*b.y; acc[2][2] += a.z*b.z; acc[2][3] += a.z*b.w;
    acc[3][0] += a.w*b.x; acc[3][1] += a.w*b.y; acc[3][2] += a.w*b.z; acc[3][3] += a.w*b.w;
  }
  #pragma unroll
  for (int r = 0; r < 4; ++r) {
    size_t off = (size_t)(p0 + ty*4 + r) * Q + q0 + tx*4;
    float4 co = *(const float4*)&Cold[off];
    float4 v = { co.x - acc[r][0], co.y - acc[r][1], co.z - acc[r][2], co.w - acc[r][3] };
    *(float4*)&Cnew[off] = v;
  }
}

// ---------------- reduces ----------------
__device__ __forceinline__ void gelu_both(float xx, float& g, float& gp) {
  const float c = 0.7978845608028654f;
  const float a = 0.044715f;
  float x2 = xx * xx;
  float u = c * (xx + a * xx * x2);
  float t = tanhf(u);
  g  = 0.5f * xx * (1.f + t);
  gp = 0.5f * (1.f + t) + 0.5f * xx * (1.f - t * t) * c * (1.f + 3.f * a * x2);
}

// H = sum(49 slices) + b1; G = gelu(H); Gp = gelu'(H)   [64,512]
__global__ __launch_bounds__(256) void red_gelu(
    const float* __restrict__ Hp, const float* __restrict__ b1,
    float* __restrict__ G, float* __restrict__ Gp) {
  int j = blockIdx.x * 256 + threadIdx.x;    // < 32768
  float s = 0.f;
  #pragma unroll
  for (int t = 0; t < 49; ++t) s += Hp[(size_t)t * 32768 + j];
  float x = s + b1[j & 511];
  float g, gp;
  gelu_both(x, g, gp);
  G[j] = g; Gp[j] = gp;
}

// Dw = wc * 2 * (sum(8 slices) + b2 - V)   [64,3136]
__global__ __launch_bounds__(256) void red_D(
    const float* __restrict__ Dp, const float* __restrict__ b2,
    const float* __restrict__ V, float* __restrict__ Dw, float wc) {
  int j = blockIdx.x * 256 + threadIdx.x;    // < 200704
  float s = 0.f;
  #pragma unroll
  for (int t = 0; t < 8; ++t) s += Dp[(size_t)t * 200704 + j];
  int i = j / DM;
  int d = j - i * DM;
  float pred = s + b2[d];
  Dw[j] = wc * 2.f * (pred - V[j]);
}

// Ew = sum(49 slices) * Gp   [64,512]
__global__ __launch_bounds__(256) void red_E(
    const float* __restrict__ Ep, const float* __restrict__ Gp,
    float* __restrict__ Ew) {
  int j = blockIdx.x * 256 + threadIdx.x;    // < 32768
  float s = 0.f;
  #pragma unroll
  for (int t = 0; t < 49; ++t) s += Ep[(size_t)t * 32768 + j];
  Ew[j] = s * Gp[j];
}

// Y = sum(8 slices) + b2n; out flat = Y flat (reference does a raw reshape
// [T, D_MODEL] -> [T,C,H,W] with NO transpose), so direct contiguous store.
__global__ __launch_bounds__(256) void red_Y(
    const float* __restrict__ Dp, const float* __restrict__ b2n,
    float* __restrict__ out, int t0) {
  int j = blockIdx.x * 256 + threadIdx.x;    // < 200704
  float s = 0.f;
  #pragma unroll
  for (int t = 0; t < 8; ++t) s += Dp[(size_t)t * 200704 + j];
  int i = j / DM;
  int d = j - i * DM;
  float y = s + b2n[d];
  out[(size_t)t0 * DM + j] = y;
}

// b2n = b2 - colsum(Dw); b1n = b1 - colsum(Ew)
__global__ __launch_bounds__(256) void upd_bias(
    const float* __restrict__ Dw, const float* __restrict__ Ew,
    const float* __restrict__ b2o, const float* __restrict__ b1o,
    float* __restrict__ b2n, float* __restrict__ b1n) {
  int j = blockIdx.x * 256 + threadIdx.x;
  if (j < DM) {
    float s = 0.f;
    #pragma unroll
    for (int i = 0; i < 64; ++i) s += Dw[(size_t)i * DM + j];
    b2n[j] = b2o[j] - s;
  } else if (j < DM + DH) {
    int q = j - DM;
    float s = 0.f;
    #pragma unroll
    for (int i = 0; i < 64; ++i) s += Ew[(size_t)i * DH + q];
    b1n[q] = b1o[q] - s;
  }
}

extern "C" void kernel_launch(void* const* d_in, const int* in_sizes, int n_in,
                              void* d_out, int out_size, void* d_ws, size_t ws_size,
                              hipStream_t stream) {
  const float* x  = (const float*)d_in[0];
  const float* wk = (const float*)d_in[1];
  const float* bk = (const float*)d_in[2];
  const float* wv = (const float*)d_in[3];
  const float* bv = (const float*)d_in[4];
  const float* sk = (const float*)d_in[5];
  const float* sv = (const float*)d_in[6];
  const float* W1 = (const float*)d_in[7];
  const float* b1 = (const float*)d_in[8];
  const float* W2 = (const float*)d_in[9];
  const float* b2 = (const float*)d_in[10];
  float* out = (float*)d_out;
  float* ws  = (float*)d_ws;

  // workspace layout (floats)
  float* nk      = ws;                 // 1,605,632
  float* nv      = ws + 1605632;       // 1,605,632
  float* W1buf[2] = { ws + 3211264, ws + 4816896 };   // 1,605,632 each
  float* W2buf[2] = { ws + 6422528, ws + 8028160 };   // 1,605,632 each
  float* Spart   = ws + 9633792;       // 1,605,632 (shared: 49x[64,512] or 8x[64,3136])
  float* G       = ws + 11239424;      // 32768
  float* Gp      = ws + 11272192;      // 32768
  float* Ew      = ws + 11304960;      // 32768
  float* Dw      = ws + 11337728;      // 200704
  float* b1buf[2] = { ws + 11538432, ws + 11538944 }; // 512 each
  float* b2buf[2] = { ws + 11539456, ws + 11542592 }; // 3136 each

  hipMemcpyAsync(W1buf[0], W1, sizeof(float) * DM * DH, hipMemcpyDeviceToDevice, stream);
  hipMemcpyAsync(b1buf[0], b1, sizeof(float) * DH,      hipMemcpyDeviceToDevice, stream);
  hipMemcpyAsync(W2buf[0], W2, sizeof(float) * DH * DM, hipMemcpyDeviceToDevice, stream);
  hipMemcpyAsync(b2buf[0], b2, sizeof(float) * DM,      hipMemcpyDeviceToDevice, stream);

  conv_rms<<<1568, 256, 0, stream>>>(x, wk, bk, wv, bv, sk, sv, nk, nv);

  // weights[i] = ETA0 * ALPHA^i * (ALPHA^63 / ALPHA^i) = ETA0 * ALPHA^63 (constant)
  float wc = (float)(0.1 * pow(0.9, 63.0));

  for (int ch = 0; ch < 8; ++ch) {
    const float* K = nk + (size_t)ch * 64 * DM;
    const float* V = nv + (size_t)ch * 64 * DM;
    int cur = ch & 1, nxt = cur ^ 1;
    float* W1c = W1buf[cur]; float* W1n = W1buf[nxt];
    float* W2c = W2buf[cur]; float* W2n = W2buf[nxt];
    float* b1c = b1buf[cur]; float* b1n = b1buf[nxt];
    float* b2c = b2buf[cur]; float* b2n = b2buf[nxt];

    // 1. Hpart = K @ W1c              [64,3136]@[3136,512]
    mm64_nn<<<dim3(8, 49), 256, 0, stream>>>(K, DM, W1c, DH, Spart, DH);
    // 2. G, Gp
    red_gelu<<<128, 256, 0, stream>>>(Spart, b1c, G, Gp);
    // 3. Dpart = G @ W2c              [64,512]@[512,3136]
    mm64_nn<<<dim3(49, 8), 256, 0, stream>>>(G, DH, W2c, DM, Spart, DM);
    // 4. Dw = wc*2*(pred - V)
    red_D<<<784, 256, 0, stream>>>(Spart, b2c, V, Dw, wc);
    // 5. Epart = Dw @ W2c^T           [64,3136]@[3136,512]
    mm64_nt<<<dim3(8, 49), 256, 0, stream>>>(Dw, DM, W2c, DM, Spart, DH);
    // 6. Ew = Epart_sum * Gp
    red_E<<<128, 256, 0, stream>>>(Spart, Gp, Ew);
    // 7. bias updates
    upd_bias<<<15, 256, 0, stream>>>(Dw, Ew, b2c, b1c, b2n, b1n);
    // 8. W2n = W2c - G^T Dw           [512,3136]
    upd64<<<dim3(49, 8), 256, 0, stream>>>(G, DH, Dw, DM, W2c, W2n);
    // 9. W1n = W1c - K^T Ew           [3136,512]
    upd64<<<dim3(8, 49), 256, 0, stream>>>(K, DM, Ew, DH, W1c, W1n);
    // 10. Hpart = K @ W1n
    mm64_nn<<<dim3(8, 49), 256, 0, stream>>>(K, DM, W1n, DH, Spart, DH);
    // 11. G2 = gelu(H + b1n)  (Gp overwritten, unused from here)
    red_gelu<<<128, 256, 0, stream>>>(Spart, b1n, G, Gp);
    // 12. Ypart = G2 @ W2n
    mm64_nn<<<dim3(49, 8), 256, 0, stream>>>(G, DH, W2n, DM, Spart, DM);
    // 13. out = Ypart_sum + b2n (raw reshape, no transpose)
    red_Y<<<784, 256, 0, stream>>>(Spart, b2n, out, ch * 64);
  }
}